// Round 8
// baseline (267.828 us; speedup 1.0000x reference)
//
#include <hip/hip_runtime.h>
#include <math.h>

#define HEADS 16
#define DHEAD 64
#define DIMM 1024
#define NQKV 3072
#define NB 2
#define SEQ 2048
#define MROWS 4096   // NB*SEQ

typedef unsigned short ushort_t;
typedef unsigned int uint_t;
typedef __attribute__((ext_vector_type(8))) short short8;
typedef __attribute__((ext_vector_type(8))) unsigned short u16x8;
typedef __attribute__((ext_vector_type(16))) float f32x16;

__device__ __forceinline__ ushort_t f2bf(float f) {
  uint_t u = __float_as_uint(f);
  u += 0x7fffu + ((u >> 16) & 1u);   // RNE
  return (ushort_t)(u >> 16);
}

__device__ __forceinline__ uint_t cvtpk_bf16(float lo, float hi) {
  uint_t r;
  asm("v_cvt_pk_bf16_f32 %0, %1, %2" : "=v"(r) : "v"(lo), "v"(hi));
  return r;
}

__device__ __forceinline__ f32x16 mfma32(short8 a, short8 b, f32x16 c) {
  return __builtin_amdgcn_mfma_f32_32x32x16_bf16(a, b, c, 0, 0, 0);
}

__device__ __forceinline__ void gload_lds16(const void* g, void* l) {
  __builtin_amdgcn_global_load_lds(
      (const __attribute__((address_space(1))) void*)g,
      (__attribute__((address_space(3))) void*)l, 16, 0, 0);
}

// ---------------- K1: RMSNorm -> xn bf16 only ----------------
__global__ __launch_bounds__(256) void k_rmsnorm(const float* __restrict__ x,
                                                 const float* __restrict__ gamma,
                                                 ushort_t* __restrict__ xn_bf) {
  int row = blockIdx.x;
  int t = threadIdx.x;
  float4 v = reinterpret_cast<const float4*>(x + (size_t)row * DIMM)[t];
  float ss = v.x * v.x + v.y * v.y + v.z * v.z + v.w * v.w;
#pragma unroll
  for (int o = 32; o >= 1; o >>= 1) ss += __shfl_xor(ss, o, 64);
  __shared__ float red[4];
  if ((t & 63) == 0) red[t >> 6] = ss;
  __syncthreads();
  ss = red[0] + red[1] + red[2] + red[3];
  float s = 32.0f / fmaxf(sqrtf(ss), 1e-12f);
  float4 g = reinterpret_cast<const float4*>(gamma)[t];
  ushort4 ob;
  ob.x = f2bf(v.x * s * g.x);
  ob.y = f2bf(v.y * s * g.y);
  ob.z = f2bf(v.z * s * g.z);
  ob.w = f2bf(v.w * s * g.w);
  *reinterpret_cast<ushort4*>(xn_bf + (size_t)row * DIMM + t * 4) = ob;
}

// ---------------- pack w_mix|w_gates -> wt[32][1024] bf16 (transposed) ----------------
__global__ __launch_bounds__(256) void k_pack_w(const float* __restrict__ w_mix,
                                                const float* __restrict__ w_gates,
                                                ushort_t* __restrict__ wt) {
  int o = blockIdx.x;   // 0..31
  const float* w = (o < HEADS) ? (w_mix + o) : (w_gates + (o - HEADS));
  for (int k = threadIdx.x; k < DIMM; k += 256)
    wt[(size_t)o * DIMM + k] = f2bf(w[(size_t)k * HEADS]);
}

// ---------------- mixgates via MFMA ----------------
__global__ __launch_bounds__(64) void k_mixgates_mfma(const ushort_t* __restrict__ xn_bf,
                                                      const ushort_t* __restrict__ wt,
                                                      const float* __restrict__ b_mix,
                                                      const float* __restrict__ b_gates,
                                                      float* __restrict__ mg) {
  const int l = threadIdx.x;
  const int ln = l & 31;
  const int hi = l >> 5;
  const int m0 = blockIdx.x * 32;
  const uint4* arow = reinterpret_cast<const uint4*>(xn_bf + (size_t)(m0 + ln) * DIMM);
  const uint4* brow = reinterpret_cast<const uint4*>(wt + (size_t)ln * DIMM);
  f32x16 acc;
#pragma unroll
  for (int r = 0; r < 16; ++r) acc[r] = 0.f;
#pragma unroll 8
  for (int ks = 0; ks < 64; ++ks) {
    uint4 ta = arow[ks * 2 + hi];
    uint4 tb = brow[ks * 2 + hi];
    acc = mfma32(*reinterpret_cast<short8*>(&ta), *reinterpret_cast<short8*>(&tb), acc);
  }
  float bias = (ln < HEADS) ? b_mix[ln] : b_gates[ln - HEADS];
#pragma unroll
  for (int r = 0; r < 16; ++r) {
    int row = m0 + (r & 3) + 8 * (r >> 2) + 4 * hi;
    float val = acc[r] + bias;
    mg[(size_t)row * 32 + ln] = 1.f / (1.f + __expf(-val));
  }
}

// ---------------- transpose-convert: in [K][N] fp32 -> outT [N][K] bf16 ----------------
__global__ __launch_bounds__(256) void k_transpose_bf(const float* __restrict__ in,
                                                      ushort_t* __restrict__ outT,
                                                      int N, int K) {
  __shared__ float tile[32][33];
  int n0 = blockIdx.x * 32, k0 = blockIdx.y * 32;
  int t = threadIdx.x;
  int r = t >> 3, c4 = (t & 7) * 4;
  float4 v = *reinterpret_cast<const float4*>(in + (size_t)(k0 + r) * N + n0 + c4);
  tile[r][c4 + 0] = v.x; tile[r][c4 + 1] = v.y; tile[r][c4 + 2] = v.z; tile[r][c4 + 3] = v.w;
  __syncthreads();
  ushort4 o;
  o.x = f2bf(tile[c4 + 0][r]);
  o.y = f2bf(tile[c4 + 1][r]);
  o.z = f2bf(tile[c4 + 2][r]);
  o.w = f2bf(tile[c4 + 3][r]);
  *reinterpret_cast<ushort4*>(outT + (size_t)(n0 + r) * K + k0 + c4) = o;
}

// ---------------- bf16 MFMA GEMM, 2-phase single-barrier pipeline ----------------
// C[M,NCOLS] = A[M,1024] @ Bt[NCOLS,1024]^T. 128x128 tile, BK=64, 4 waves (2x2),
// LDS double-buffered (64KB). Per K-step: issue next-tile global_load_lds into
// buf^1, ds_read+MFMA on buf, then s_waitcnt vmcnt(0) + raw s_barrier (ONE
// barrier/step; staging loads hide under compute). XCD-swizzled block id.
// MODE 0: QKV epilogue (q/k bf16, v lerped bf16, orig_v fp32)
// MODE 1: plain fp32 store
template <int NCOLS, int MODE>
__global__ __launch_bounds__(256, 2) void k_gemm_bf(const ushort_t* __restrict__ A,
                                                    const ushort_t* __restrict__ Bt,
                                                    ushort_t* __restrict__ q_bf,
                                                    ushort_t* __restrict__ k_bf,
                                                    ushort_t* __restrict__ v_bf,
                                                    float* __restrict__ orig_v,
                                                    const float* __restrict__ vr,
                                                    const float* __restrict__ mg,
                                                    float* __restrict__ outp) {
  __shared__ __align__(16) ushort_t As[2][128 * 64];
  __shared__ __align__(16) ushort_t Bs[2][128 * 64];
  const int t = threadIdx.x;
  const int w = t >> 6;
  const int l = t & 63;
  const int ln = l & 31;
  const int hi = l >> 5;
  const int wm = w >> 1, wn = w & 1;

  // XCD-aware swizzle of flat block id (nwg % 8 == 0 for both instances)
  constexpr int NBX = NCOLS / 128;
  constexpr int NWG = NBX * (MROWS / 128);
  int flat = blockIdx.y * NBX + blockIdx.x;
  int swz = (flat & 7) * (NWG / 8) + (flat >> 3);
  const int m0 = (swz / NBX) * 128, n0 = (swz % NBX) * 128;

  f32x16 acc00, acc01, acc10, acc11;
#pragma unroll
  for (int r = 0; r < 16; ++r) { acc00[r] = 0.f; acc01[r] = 0.f; acc10[r] = 0.f; acc11[r] = 0.f; }

  const int srow8 = l >> 3;   // 0..7
  const int cp = l & 7;       // stored chunk position

  auto stage = [&](int buf, int k0) {
#pragma unroll
    for (int i = 0; i < 4; ++i) {
      int rowa = (i * 4 + w) * 8 + srow8;
      const ushort_t* ga = A + (size_t)(m0 + rowa) * DIMM + k0 + ((cp ^ (rowa & 7)) * 8);
      gload_lds16(ga, &As[buf][(i * 4 + w) * 512]);
      const ushort_t* gb = Bt + (size_t)(n0 + rowa) * DIMM + k0 + ((cp ^ (rowa & 7)) * 8);
      gload_lds16(gb, &Bs[buf][(i * 4 + w) * 512]);
    }
  };

  stage(0, 0);
  asm volatile("s_waitcnt vmcnt(0)" ::: "memory");
  __builtin_amdgcn_s_barrier();

  for (int kt = 0; kt < DIMM / 64; ++kt) {
    int cur = kt & 1;
    if (kt + 1 < DIMM / 64) stage(cur ^ 1, (kt + 1) * 64);   // prefetch next tile
    const ushort_t* as = As[cur];
    const ushort_t* bs = Bs[cur];
#pragma unroll
    for (int ks = 0; ks < 4; ++ks) {
      int cl = ks * 2 + hi;
      int ra0 = wm * 64 + ln;
      int ra1 = wm * 64 + 32 + ln;
      int rb0 = wn * 64 + ln;
      int rb1 = wn * 64 + 32 + ln;
      short8 af0 = *reinterpret_cast<const short8*>(&as[ra0 * 64 + ((cl ^ (ra0 & 7)) * 8)]);
      short8 af1 = *reinterpret_cast<const short8*>(&as[ra1 * 64 + ((cl ^ (ra1 & 7)) * 8)]);
      short8 bf0 = *reinterpret_cast<const short8*>(&bs[rb0 * 64 + ((cl ^ (rb0 & 7)) * 8)]);
      short8 bf1 = *reinterpret_cast<const short8*>(&bs[rb1 * 64 + ((cl ^ (rb1 & 7)) * 8)]);
      acc00 = mfma32(af0, bf0, acc00);
      acc01 = mfma32(af0, bf1, acc01);
      acc10 = mfma32(af1, bf0, acc10);
      acc11 = mfma32(af1, bf1, acc11);
    }
    // ds_reads of buf[cur] are consumed (lgkmcnt waits precede the MFMAs), so
    // after this barrier buf[cur] may be overwritten; drain our staging loads.
    asm volatile("s_waitcnt vmcnt(0)" ::: "memory");
    __builtin_amdgcn_s_barrier();
  }

  // ---------------- epilogue ----------------
  auto do_tile = [&](const f32x16& a, int mt, int nt) {
    int nb = n0 + wn * 64 + nt * 32;       // wave-uniform base col
    if (MODE == 1) {
#pragma unroll
      for (int r = 0; r < 16; ++r) {
        int m_loc = wm * 64 + mt * 32 + (r & 3) + 8 * (r >> 2) + 4 * hi;
        int row = m0 + m_loc;
        outp[(size_t)row * NCOLS + nb + ln] = a[r];
      }
    } else {
      int part = nb >> 10;
      int hh = (nb & 1023) >> 6;
      int ddb = (nb & 63) + ln;
#pragma unroll
      for (int r = 0; r < 16; ++r) {
        int m_loc = wm * 64 + mt * 32 + (r & 3) + 8 * (r >> 2) + 4 * hi;
        int row = m0 + m_loc;
        int b_i = row >> 11, n_i = row & 2047;
        size_t idx = (((size_t)(b_i * HEADS + hh)) * SEQ + n_i) * DHEAD + ddb;
        float val = a[r];
        if (part == 0) {
          q_bf[idx] = f2bf(val);
        } else if (part == 1) {
          k_bf[idx] = f2bf(val);
        } else {
          orig_v[idx] = val;
          float mixv = mg[(size_t)row * 32 + hh];
          float fv = val + mixv * (vr[idx] - val);
          v_bf[idx] = f2bf(fv);
        }
      }
    }
  };
  do_tile(acc00, 0, 0);
  do_tile(acc01, 0, 1);
  do_tile(acc10, 1, 0);
  do_tile(acc11, 1, 1);
}

// ---------------- K3: bf16 MFMA flash attention + sigmoid gating ----------------
__global__ __launch_bounds__(256, 2) void k_attn(const ushort_t* __restrict__ qb,
                                                 const ushort_t* __restrict__ kb,
                                                 const ushort_t* __restrict__ vb,
                                                 const float* __restrict__ mg,
                                                 ushort_t* __restrict__ attn_bf) {
  __shared__ uint4 Ksm[64 * 8];     // [row][swz chunk]
  __shared__ uint_t Vtsm[64 * 32];  // [d][...] transposed V, pair-packed

  const int t = threadIdx.x;
  const int w = t >> 6;
  const int l = t & 63;
  const int hi = l >> 5;
  const int ln = l & 31;
  const int bh = blockIdx.y;
  const int q0 = blockIdx.x * 128;
  const int b_i = bh >> 4, h = bh & 15;

  const size_t base = (size_t)bh * SEQ * DHEAD;

  short8 qf[4];
  {
    const uint4* qsrc = reinterpret_cast<const uint4*>(qb + base + (size_t)(q0 + w * 32 + ln) * DHEAD);
#pragma unroll
    for (int ds = 0; ds < 4; ++ds) {
      uint4 tq = qsrc[ds * 2 + hi];
      qf[ds] = *reinterpret_cast<short8*>(&tq);
    }
  }

  f32x16 o0, o1;
#pragma unroll
  for (int r = 0; r < 16; ++r) { o0[r] = 0.f; o1[r] = 0.f; }
  float m_run = -3.0e38f, l_run = 0.f;

  const int sr = t >> 2;
  const int sc = (t & 3) * 2;
  const int vp = t & 31;
  const int vg = t >> 5;

  const uint4* kg = reinterpret_cast<const uint4*>(kb + base);
  const uint4* vgp = reinterpret_cast<const uint4*>(vb + base);

  uint4 kA = kg[(size_t)sr * 8 + sc];
  uint4 kB = kg[(size_t)sr * 8 + sc + 1];
  uint4 vA = vgp[(size_t)(vp * 2) * 8 + vg];
  uint4 vB = vgp[(size_t)(vp * 2 + 1) * 8 + vg];

  for (int kt = 0; kt < SEQ / 64; ++kt) {
    __syncthreads();
    Ksm[sr * 8 + (sc ^ (sr & 7))] = kA;
    Ksm[sr * 8 + ((sc + 1) ^ (sr & 7))] = kB;
    {
      u16x8 a = *reinterpret_cast<u16x8*>(&vA);
      u16x8 b = *reinterpret_cast<u16x8*>(&vB);
#pragma unroll
      for (int j = 0; j < 8; ++j) {
        uint_t pw = (uint_t)a[j] | ((uint_t)b[j] << 16);
        int d = vg * 8 + j;
        Vtsm[d * 32 + (((vp >> 2) ^ j) << 2) + (vp & 3)] = pw;
      }
    }
    __syncthreads();

    if (kt + 1 < SEQ / 64) {
      size_t rb = (size_t)((kt + 1) * 64);
      kA = kg[(rb + sr) * 8 + sc];
      kB = kg[(rb + sr) * 8 + sc + 1];
      vA = vgp[(rb + vp * 2) * 8 + vg];
      vB = vgp[(rb + vp * 2 + 1) * 8 + vg];
    }

    f32x16 s0, s1;
#pragma unroll
    for (int r = 0; r < 16; ++r) { s0[r] = 0.f; s1[r] = 0.f; }
#pragma unroll
    for (int ds = 0; ds < 4; ++ds) {
      int ch = ds * 2 + hi;
      uint4 ta = Ksm[ln * 8 + (ch ^ (ln & 7))];
      s0 = mfma32(*reinterpret_cast<short8*>(&ta), qf[ds], s0);
      int r1 = 32 + ln;
      uint4 tb = Ksm[r1 * 8 + (ch ^ (r1 & 7))];
      s1 = mfma32(*reinterpret_cast<short8*>(&tb), qf[ds], s1);
    }

    float u[32];
#pragma unroll
    for (int r = 0; r < 16; ++r) { u[r] = s0[r]; u[16 + r] = s1[r]; }
    float mx = u[0];
#pragma unroll
    for (int r = 1; r < 32; ++r) mx = fmaxf(mx, u[r]);
    mx *= 0.125f;
    mx = fmaxf(mx, __shfl_xor(mx, 32, 64));
    float mnew = fmaxf(m_run, mx);
    float corr = __expf(m_run - mnew);
    m_run = mnew;
    float p[32];
    float rs = 0.f;
#pragma unroll
    for (int r = 0; r < 32; ++r) {
      p[r] = __expf(fmaf(u[r], 0.125f, -mnew));
      rs += p[r];
    }
    rs += __shfl_xor(rs, 32, 64);
    l_run = fmaf(l_run, corr, rs);
    o0 *= corr;
    o1 *= corr;

    short8 pa[4];
#pragma unroll
    for (int ks = 0; ks < 4; ++ks) {
      int g = ks * 8;
      uint_t w0 = cvtpk_bf16(p[g + 0], p[g + 1]);
      uint_t w1 = cvtpk_bf16(p[g + 2], p[g + 3]);
      uint_t w2 = cvtpk_bf16(p[g + 4], p[g + 5]);
      uint_t w3 = cvtpk_bf16(p[g + 6], p[g + 7]);
      asm volatile("v_permlane32_swap_b32 %0, %1" : "+v"(w0), "+v"(w2));
      asm volatile("v_permlane32_swap_b32 %0, %1" : "+v"(w1), "+v"(w3));
      uint_t tw[4] = {w0, w1, w2, w3};
      pa[ks] = *reinterpret_cast<short8*>(tw);
    }

#pragma unroll
    for (int ks = 0; ks < 4; ++ks) {
      int ch = ks * 2 + hi;
      uint4 ta = *reinterpret_cast<uint4*>(&Vtsm[ln * 32 + ((ch ^ (ln & 7)) << 2)]);
      o0 = mfma32(*reinterpret_cast<short8*>(&ta), pa[ks], o0);
      int d1 = 32 + ln;
      uint4 tb = *reinterpret_cast<uint4*>(&Vtsm[d1 * 32 + ((ch ^ (d1 & 7)) << 2)]);
      o1 = mfma32(*reinterpret_cast<short8*>(&tb), pa[ks], o1);
    }
  }

  int n_i = q0 + w * 32 + ln;
  int rowg = b_i * SEQ + n_i;
  float gate = mg[(size_t)rowg * 32 + HEADS + h];
  float f = gate / l_run;
  ushort_t* dst = attn_bf + (size_t)rowg * DIMM + h * DHEAD;
#pragma unroll
  for (int g = 0; g < 4; ++g) {
    uint2 p0;
    p0.x = cvtpk_bf16(o0[4 * g] * f, o0[4 * g + 1] * f);
    p0.y = cvtpk_bf16(o0[4 * g + 2] * f, o0[4 * g + 3] * f);
    *reinterpret_cast<uint2*>(dst + g * 8 + hi * 4) = p0;
    uint2 p1;
    p1.x = cvtpk_bf16(o1[4 * g] * f, o1[4 * g + 1] * f);
    p1.y = cvtpk_bf16(o1[4 * g + 2] * f, o1[4 * g + 3] * f);
    *reinterpret_cast<uint2*>(dst + 32 + g * 8 + hi * 4) = p1;
  }
}

// ---------------- launch ----------------
extern "C" void kernel_launch(void* const* d_in, const int* in_sizes, int n_in,
                              void* d_out, int out_size, void* d_ws, size_t ws_size,
                              hipStream_t stream) {
  const float* x       = (const float*)d_in[0];
  const float* vr      = (const float*)d_in[1];
  const float* gamma   = (const float*)d_in[2];
  const float* w_qkv   = (const float*)d_in[3];
  const float* w_mix   = (const float*)d_in[4];
  const float* b_mix   = (const float*)d_in[5];
  const float* w_gates = (const float*)d_in[6];
  const float* b_gates = (const float*)d_in[7];
  const float* w_out   = (const float*)d_in[8];

  float* out = (float*)d_out;
  float* orig_v = out + (size_t)MROWS * DIMM;   // second tuple output [b,h,n,d] fp32

  const size_t BUF = (size_t)MROWS * DIMM;      // 4,194,304 elements
  char* wsb = (char*)d_ws;
  ushort_t* xn_bf   = (ushort_t*)wsb;                     wsb += BUF * 2;          // 8.39 MB
  ushort_t* q_bf    = (ushort_t*)wsb;                     wsb += BUF * 2;
  ushort_t* k_bf    = (ushort_t*)wsb;                     wsb += BUF * 2;
  ushort_t* v_bf    = (ushort_t*)wsb;                     wsb += BUF * 2;
  ushort_t* attn_bf = (ushort_t*)wsb;                     wsb += BUF * 2;
  ushort_t* wqkv_t  = (ushort_t*)wsb;                     wsb += (size_t)NQKV * DIMM * 2;  // 6.29 MB
  ushort_t* wout_t  = (ushort_t*)wsb;                     wsb += (size_t)DIMM * DIMM * 2;  // 2.10 MB
  ushort_t* wt_mg   = (ushort_t*)wsb;                     wsb += (size_t)32 * DIMM * 2;    // 64 KB
  float*    mg      = (float*)wsb;                        wsb += (size_t)MROWS * 32 * 4;   // 0.52 MB

  k_pack_w<<<dim3(32), dim3(256), 0, stream>>>(w_mix, w_gates, wt_mg);
  k_transpose_bf<<<dim3(NQKV / 32, DIMM / 32), dim3(256), 0, stream>>>(w_qkv, wqkv_t, NQKV, DIMM);
  k_transpose_bf<<<dim3(DIMM / 32, DIMM / 32), dim3(256), 0, stream>>>(w_out, wout_t, DIMM, DIMM);
  k_rmsnorm<<<dim3(MROWS), dim3(256), 0, stream>>>(x, gamma, xn_bf);
  k_mixgates_mfma<<<dim3(MROWS / 32), dim3(64), 0, stream>>>(xn_bf, wt_mg, b_mix, b_gates, mg);
  k_gemm_bf<NQKV, 0><<<dim3(NQKV / 128, MROWS / 128), dim3(256), 0, stream>>>(
      xn_bf, wqkv_t, q_bf, k_bf, v_bf, orig_v, vr, mg, nullptr);
  k_attn<<<dim3(SEQ / 128, NB * HEADS), dim3(256), 0, stream>>>(q_bf, k_bf, v_bf, mg, attn_bf);
  k_gemm_bf<DIMM, 1><<<dim3(DIMM / 128, MROWS / 128), dim3(256), 0, stream>>>(
      attn_bf, wout_t, nullptr, nullptr, nullptr, nullptr, nullptr, nullptr, out);
}

// Round 9
// 260.911 us; speedup vs baseline: 1.0265x; 1.0265x over previous
//
#include <hip/hip_runtime.h>
#include <math.h>

#define HEADS 16
#define DHEAD 64
#define DIMM 1024
#define NQKV 3072
#define NB 2
#define SEQ 2048
#define MROWS 4096   // NB*SEQ

typedef unsigned short ushort_t;
typedef unsigned int uint_t;
typedef __attribute__((ext_vector_type(8))) short short8;
typedef __attribute__((ext_vector_type(8))) unsigned short u16x8;
typedef __attribute__((ext_vector_type(16))) float f32x16;

__device__ __forceinline__ ushort_t f2bf(float f) {
  uint_t u = __float_as_uint(f);
  u += 0x7fffu + ((u >> 16) & 1u);   // RNE
  return (ushort_t)(u >> 16);
}

__device__ __forceinline__ uint_t cvtpk_bf16(float lo, float hi) {
  uint_t r;
  asm("v_cvt_pk_bf16_f32 %0, %1, %2" : "=v"(r) : "v"(lo), "v"(hi));
  return r;
}

__device__ __forceinline__ f32x16 mfma32(short8 a, short8 b, f32x16 c) {
  return __builtin_amdgcn_mfma_f32_32x32x16_bf16(a, b, c, 0, 0, 0);
}

__device__ __forceinline__ void gload_lds16(const void* g, void* l) {
  __builtin_amdgcn_global_load_lds(
      (const __attribute__((address_space(1))) void*)g,
      (__attribute__((address_space(3))) void*)l, 16, 0, 0);
}

// ---------------- K1: RMSNorm -> xn bf16 only ----------------
__global__ __launch_bounds__(256) void k_rmsnorm(const float* __restrict__ x,
                                                 const float* __restrict__ gamma,
                                                 ushort_t* __restrict__ xn_bf) {
  int row = blockIdx.x;
  int t = threadIdx.x;
  float4 v = reinterpret_cast<const float4*>(x + (size_t)row * DIMM)[t];
  float ss = v.x * v.x + v.y * v.y + v.z * v.z + v.w * v.w;
#pragma unroll
  for (int o = 32; o >= 1; o >>= 1) ss += __shfl_xor(ss, o, 64);
  __shared__ float red[4];
  if ((t & 63) == 0) red[t >> 6] = ss;
  __syncthreads();
  ss = red[0] + red[1] + red[2] + red[3];
  float s = 32.0f / fmaxf(sqrtf(ss), 1e-12f);
  float4 g = reinterpret_cast<const float4*>(gamma)[t];
  ushort4 ob;
  ob.x = f2bf(v.x * s * g.x);
  ob.y = f2bf(v.y * s * g.y);
  ob.z = f2bf(v.z * s * g.z);
  ob.w = f2bf(v.w * s * g.w);
  *reinterpret_cast<ushort4*>(xn_bf + (size_t)row * DIMM + t * 4) = ob;
}

// ---------------- pack w_mix|w_gates -> wt[32][1024] bf16 (transposed) ----------------
__global__ __launch_bounds__(256) void k_pack_w(const float* __restrict__ w_mix,
                                                const float* __restrict__ w_gates,
                                                ushort_t* __restrict__ wt) {
  int o = blockIdx.x;   // 0..31
  const float* w = (o < HEADS) ? (w_mix + o) : (w_gates + (o - HEADS));
  for (int k = threadIdx.x; k < DIMM; k += 256)
    wt[(size_t)o * DIMM + k] = f2bf(w[(size_t)k * HEADS]);
}

// ---------------- mixgates via MFMA ----------------
__global__ __launch_bounds__(64) void k_mixgates_mfma(const ushort_t* __restrict__ xn_bf,
                                                      const ushort_t* __restrict__ wt,
                                                      const float* __restrict__ b_mix,
                                                      const float* __restrict__ b_gates,
                                                      float* __restrict__ mg) {
  const int l = threadIdx.x;
  const int ln = l & 31;
  const int hi = l >> 5;
  const int m0 = blockIdx.x * 32;
  const uint4* arow = reinterpret_cast<const uint4*>(xn_bf + (size_t)(m0 + ln) * DIMM);
  const uint4* brow = reinterpret_cast<const uint4*>(wt + (size_t)ln * DIMM);
  f32x16 acc;
#pragma unroll
  for (int r = 0; r < 16; ++r) acc[r] = 0.f;
#pragma unroll 8
  for (int ks = 0; ks < 64; ++ks) {
    uint4 ta = arow[ks * 2 + hi];
    uint4 tb = brow[ks * 2 + hi];
    acc = mfma32(*reinterpret_cast<short8*>(&ta), *reinterpret_cast<short8*>(&tb), acc);
  }
  float bias = (ln < HEADS) ? b_mix[ln] : b_gates[ln - HEADS];
#pragma unroll
  for (int r = 0; r < 16; ++r) {
    int row = m0 + (r & 3) + 8 * (r >> 2) + 4 * hi;
    float val = acc[r] + bias;
    mg[(size_t)row * 32 + ln] = 1.f / (1.f + __expf(-val));
  }
}

// ---------------- transpose-convert: in [K][N] fp32 -> outT [N][K] bf16 ----------------
__global__ __launch_bounds__(256) void k_transpose_bf(const float* __restrict__ in,
                                                      ushort_t* __restrict__ outT,
                                                      int N, int K) {
  __shared__ float tile[32][33];
  int n0 = blockIdx.x * 32, k0 = blockIdx.y * 32;
  int t = threadIdx.x;
  int r = t >> 3, c4 = (t & 7) * 4;
  float4 v = *reinterpret_cast<const float4*>(in + (size_t)(k0 + r) * N + n0 + c4);
  tile[r][c4 + 0] = v.x; tile[r][c4 + 1] = v.y; tile[r][c4 + 2] = v.z; tile[r][c4 + 3] = v.w;
  __syncthreads();
  ushort4 o;
  o.x = f2bf(tile[c4 + 0][r]);
  o.y = f2bf(tile[c4 + 1][r]);
  o.z = f2bf(tile[c4 + 2][r]);
  o.w = f2bf(tile[c4 + 3][r]);
  *reinterpret_cast<ushort4*>(outT + (size_t)(n0 + r) * K + k0 + c4) = o;
}

// ---------------- bf16 MFMA GEMM (m97-style 2-barrier, single buffer) ----------------
// C[M,NCOLS] = A[M,1024] @ Bt[NCOLS,1024]^T. 128x128 tile, BK=64, 4 waves (2x2).
// MODE 0: QKV epilogue (q/k bf16, v lerped bf16, orig_v fp32)
// MODE 1: plain fp32 store
template <int NCOLS, int MODE>
__global__ __launch_bounds__(256, 2) void k_gemm_bf(const ushort_t* __restrict__ A,
                                                    const ushort_t* __restrict__ Bt,
                                                    ushort_t* __restrict__ q_bf,
                                                    ushort_t* __restrict__ k_bf,
                                                    ushort_t* __restrict__ v_bf,
                                                    float* __restrict__ orig_v,
                                                    const float* __restrict__ vr,
                                                    const float* __restrict__ mg,
                                                    float* __restrict__ outp) {
  __shared__ __align__(16) ushort_t As[128 * 64];
  __shared__ __align__(16) ushort_t Bs[128 * 64];
  const int t = threadIdx.x;
  const int w = t >> 6;
  const int l = t & 63;
  const int ln = l & 31;
  const int hi = l >> 5;
  const int wm = w >> 1, wn = w & 1;
  const int m0 = blockIdx.y * 128, n0 = blockIdx.x * 128;

  f32x16 acc00, acc01, acc10, acc11;
#pragma unroll
  for (int r = 0; r < 16; ++r) { acc00[r] = 0.f; acc01[r] = 0.f; acc10[r] = 0.f; acc11[r] = 0.f; }

  const int srow8 = l >> 3;   // 0..7
  const int cp = l & 7;       // stored chunk position

  for (int k0 = 0; k0 < DIMM; k0 += 64) {
#pragma unroll
    for (int i = 0; i < 4; ++i) {
      int rowa = (i * 4 + w) * 8 + srow8;
      const ushort_t* ga = A + (size_t)(m0 + rowa) * DIMM + k0 + ((cp ^ (rowa & 7)) * 8);
      gload_lds16(ga, &As[(i * 4 + w) * 512]);
      const ushort_t* gb = Bt + (size_t)(n0 + rowa) * DIMM + k0 + ((cp ^ (rowa & 7)) * 8);
      gload_lds16(gb, &Bs[(i * 4 + w) * 512]);
    }
    __syncthreads();   // vmcnt(0) drain + visibility
#pragma unroll
    for (int ks = 0; ks < 4; ++ks) {
      int cl = ks * 2 + hi;
      int ra0 = wm * 64 + ln;
      int ra1 = wm * 64 + 32 + ln;
      int rb0 = wn * 64 + ln;
      int rb1 = wn * 64 + 32 + ln;
      short8 af0 = *reinterpret_cast<const short8*>(&As[ra0 * 64 + ((cl ^ (ra0 & 7)) * 8)]);
      short8 af1 = *reinterpret_cast<const short8*>(&As[ra1 * 64 + ((cl ^ (ra1 & 7)) * 8)]);
      short8 bf0 = *reinterpret_cast<const short8*>(&Bs[rb0 * 64 + ((cl ^ (rb0 & 7)) * 8)]);
      short8 bf1 = *reinterpret_cast<const short8*>(&Bs[rb1 * 64 + ((cl ^ (rb1 & 7)) * 8)]);
      acc00 = mfma32(af0, bf0, acc00);
      acc01 = mfma32(af0, bf1, acc01);
      acc10 = mfma32(af1, bf0, acc10);
      acc11 = mfma32(af1, bf1, acc11);
    }
    __syncthreads();   // compute done before next stage overwrites
  }

  // ---------------- epilogue ----------------
  auto do_tile = [&](const f32x16& a, int mt, int nt) {
    int nb = n0 + wn * 64 + nt * 32;       // wave-uniform base col
    if (MODE == 1) {
#pragma unroll
      for (int r = 0; r < 16; ++r) {
        int m_loc = wm * 64 + mt * 32 + (r & 3) + 8 * (r >> 2) + 4 * hi;
        int row = m0 + m_loc;
        outp[(size_t)row * NCOLS + nb + ln] = a[r];
      }
    } else {
      int part = nb >> 10;
      int hh = (nb & 1023) >> 6;
      int ddb = (nb & 63) + ln;
#pragma unroll
      for (int r = 0; r < 16; ++r) {
        int m_loc = wm * 64 + mt * 32 + (r & 3) + 8 * (r >> 2) + 4 * hi;
        int row = m0 + m_loc;
        int b_i = row >> 11, n_i = row & 2047;
        size_t idx = (((size_t)(b_i * HEADS + hh)) * SEQ + n_i) * DHEAD + ddb;
        float val = a[r];
        if (part == 0) {
          q_bf[idx] = f2bf(val);
        } else if (part == 1) {
          k_bf[idx] = f2bf(val);
        } else {
          orig_v[idx] = val;
          float mixv = mg[(size_t)row * 32 + hh];
          float fv = val + mixv * (vr[idx] - val);
          v_bf[idx] = f2bf(fv);
        }
      }
    }
  };
  do_tile(acc00, 0, 0);
  do_tile(acc01, 0, 1);
  do_tile(acc10, 1, 0);
  do_tile(acc11, 1, 1);
}

// ---------------- K3: bf16 MFMA flash attention + sigmoid gating ----------------
// T5: s_setprio(1) around the MFMA clusters (independent blocks per CU -> scheduler
// can favor MFMA-issuing waves; +4-7% measured on attn-shaped kernels, m191).
__global__ __launch_bounds__(256, 2) void k_attn(const ushort_t* __restrict__ qb,
                                                 const ushort_t* __restrict__ kb,
                                                 const ushort_t* __restrict__ vb,
                                                 const float* __restrict__ mg,
                                                 ushort_t* __restrict__ attn_bf) {
  __shared__ uint4 Ksm[64 * 8];     // [row][swz chunk]
  __shared__ uint_t Vtsm[64 * 32];  // [d][...] transposed V, pair-packed

  const int t = threadIdx.x;
  const int w = t >> 6;
  const int l = t & 63;
  const int hi = l >> 5;
  const int ln = l & 31;
  const int bh = blockIdx.y;
  const int q0 = blockIdx.x * 128;
  const int b_i = bh >> 4, h = bh & 15;

  const size_t base = (size_t)bh * SEQ * DHEAD;

  short8 qf[4];
  {
    const uint4* qsrc = reinterpret_cast<const uint4*>(qb + base + (size_t)(q0 + w * 32 + ln) * DHEAD);
#pragma unroll
    for (int ds = 0; ds < 4; ++ds) {
      uint4 tq = qsrc[ds * 2 + hi];
      qf[ds] = *reinterpret_cast<short8*>(&tq);
    }
  }

  f32x16 o0, o1;
#pragma unroll
  for (int r = 0; r < 16; ++r) { o0[r] = 0.f; o1[r] = 0.f; }
  float m_run = -3.0e38f, l_run = 0.f;

  const int sr = t >> 2;
  const int sc = (t & 3) * 2;
  const int vp = t & 31;
  const int vg = t >> 5;

  const uint4* kg = reinterpret_cast<const uint4*>(kb + base);
  const uint4* vgp = reinterpret_cast<const uint4*>(vb + base);

  uint4 kA = kg[(size_t)sr * 8 + sc];
  uint4 kB = kg[(size_t)sr * 8 + sc + 1];
  uint4 vA = vgp[(size_t)(vp * 2) * 8 + vg];
  uint4 vB = vgp[(size_t)(vp * 2 + 1) * 8 + vg];

  for (int kt = 0; kt < SEQ / 64; ++kt) {
    __syncthreads();
    Ksm[sr * 8 + (sc ^ (sr & 7))] = kA;
    Ksm[sr * 8 + ((sc + 1) ^ (sr & 7))] = kB;
    {
      u16x8 a = *reinterpret_cast<u16x8*>(&vA);
      u16x8 b = *reinterpret_cast<u16x8*>(&vB);
#pragma unroll
      for (int j = 0; j < 8; ++j) {
        uint_t pw = (uint_t)a[j] | ((uint_t)b[j] << 16);
        int d = vg * 8 + j;
        Vtsm[d * 32 + (((vp >> 2) ^ j) << 2) + (vp & 3)] = pw;
      }
    }
    __syncthreads();

    if (kt + 1 < SEQ / 64) {
      size_t rb = (size_t)((kt + 1) * 64);
      kA = kg[(rb + sr) * 8 + sc];
      kB = kg[(rb + sr) * 8 + sc + 1];
      vA = vgp[(rb + vp * 2) * 8 + vg];
      vB = vgp[(rb + vp * 2 + 1) * 8 + vg];
    }

    f32x16 s0, s1;
#pragma unroll
    for (int r = 0; r < 16; ++r) { s0[r] = 0.f; s1[r] = 0.f; }
    __builtin_amdgcn_s_setprio(1);
#pragma unroll
    for (int ds = 0; ds < 4; ++ds) {
      int ch = ds * 2 + hi;
      uint4 ta = Ksm[ln * 8 + (ch ^ (ln & 7))];
      s0 = mfma32(*reinterpret_cast<short8*>(&ta), qf[ds], s0);
      int r1 = 32 + ln;
      uint4 tb = Ksm[r1 * 8 + (ch ^ (r1 & 7))];
      s1 = mfma32(*reinterpret_cast<short8*>(&tb), qf[ds], s1);
    }
    __builtin_amdgcn_s_setprio(0);

    float u[32];
#pragma unroll
    for (int r = 0; r < 16; ++r) { u[r] = s0[r]; u[16 + r] = s1[r]; }
    float mx = u[0];
#pragma unroll
    for (int r = 1; r < 32; ++r) mx = fmaxf(mx, u[r]);
    mx *= 0.125f;
    mx = fmaxf(mx, __shfl_xor(mx, 32, 64));
    float mnew = fmaxf(m_run, mx);
    float corr = __expf(m_run - mnew);
    m_run = mnew;
    float p[32];
    float rs = 0.f;
#pragma unroll
    for (int r = 0; r < 32; ++r) {
      p[r] = __expf(fmaf(u[r], 0.125f, -mnew));
      rs += p[r];
    }
    rs += __shfl_xor(rs, 32, 64);
    l_run = fmaf(l_run, corr, rs);
    o0 *= corr;
    o1 *= corr;

    short8 pa[4];
#pragma unroll
    for (int ks = 0; ks < 4; ++ks) {
      int g = ks * 8;
      uint_t w0 = cvtpk_bf16(p[g + 0], p[g + 1]);
      uint_t w1 = cvtpk_bf16(p[g + 2], p[g + 3]);
      uint_t w2 = cvtpk_bf16(p[g + 4], p[g + 5]);
      uint_t w3 = cvtpk_bf16(p[g + 6], p[g + 7]);
      asm volatile("v_permlane32_swap_b32 %0, %1" : "+v"(w0), "+v"(w2));
      asm volatile("v_permlane32_swap_b32 %0, %1" : "+v"(w1), "+v"(w3));
      uint_t tw[4] = {w0, w1, w2, w3};
      pa[ks] = *reinterpret_cast<short8*>(tw);
    }

    __builtin_amdgcn_s_setprio(1);
#pragma unroll
    for (int ks = 0; ks < 4; ++ks) {
      int ch = ks * 2 + hi;
      uint4 ta = *reinterpret_cast<uint4*>(&Vtsm[ln * 32 + ((ch ^ (ln & 7)) << 2)]);
      o0 = mfma32(*reinterpret_cast<short8*>(&ta), pa[ks], o0);
      int d1 = 32 + ln;
      uint4 tb = *reinterpret_cast<uint4*>(&Vtsm[d1 * 32 + ((ch ^ (d1 & 7)) << 2)]);
      o1 = mfma32(*reinterpret_cast<short8*>(&tb), pa[ks], o1);
    }
    __builtin_amdgcn_s_setprio(0);
  }

  int n_i = q0 + w * 32 + ln;
  int rowg = b_i * SEQ + n_i;
  float gate = mg[(size_t)rowg * 32 + HEADS + h];
  float f = gate / l_run;
  ushort_t* dst = attn_bf + (size_t)rowg * DIMM + h * DHEAD;
#pragma unroll
  for (int g = 0; g < 4; ++g) {
    uint2 p0;
    p0.x = cvtpk_bf16(o0[4 * g] * f, o0[4 * g + 1] * f);
    p0.y = cvtpk_bf16(o0[4 * g + 2] * f, o0[4 * g + 3] * f);
    *reinterpret_cast<uint2*>(dst + g * 8 + hi * 4) = p0;
    uint2 p1;
    p1.x = cvtpk_bf16(o1[4 * g] * f, o1[4 * g + 1] * f);
    p1.y = cvtpk_bf16(o1[4 * g + 2] * f, o1[4 * g + 3] * f);
    *reinterpret_cast<uint2*>(dst + 32 + g * 8 + hi * 4) = p1;
  }
}

// ---------------- launch ----------------
extern "C" void kernel_launch(void* const* d_in, const int* in_sizes, int n_in,
                              void* d_out, int out_size, void* d_ws, size_t ws_size,
                              hipStream_t stream) {
  const float* x       = (const float*)d_in[0];
  const float* vr      = (const float*)d_in[1];
  const float* gamma   = (const float*)d_in[2];
  const float* w_qkv   = (const float*)d_in[3];
  const float* w_mix   = (const float*)d_in[4];
  const float* b_mix   = (const float*)d_in[5];
  const float* w_gates = (const float*)d_in[6];
  const float* b_gates = (const float*)d_in[7];
  const float* w_out   = (const float*)d_in[8];

  float* out = (float*)d_out;
  float* orig_v = out + (size_t)MROWS * DIMM;   // second tuple output [b,h,n,d] fp32

  const size_t BUF = (size_t)MROWS * DIMM;      // 4,194,304 elements
  char* wsb = (char*)d_ws;
  ushort_t* xn_bf   = (ushort_t*)wsb;                     wsb += BUF * 2;          // 8.39 MB
  ushort_t* q_bf    = (ushort_t*)wsb;                     wsb += BUF * 2;
  ushort_t* k_bf    = (ushort_t*)wsb;                     wsb += BUF * 2;
  ushort_t* v_bf    = (ushort_t*)wsb;                     wsb += BUF * 2;
  ushort_t* attn_bf = (ushort_t*)wsb;                     wsb += BUF * 2;
  ushort_t* wqkv_t  = (ushort_t*)wsb;                     wsb += (size_t)NQKV * DIMM * 2;  // 6.29 MB
  ushort_t* wout_t  = (ushort_t*)wsb;                     wsb += (size_t)DIMM * DIMM * 2;  // 2.10 MB
  ushort_t* wt_mg   = (ushort_t*)wsb;                     wsb += (size_t)32 * DIMM * 2;    // 64 KB
  float*    mg      = (float*)wsb;                        wsb += (size_t)MROWS * 32 * 4;   // 0.52 MB

  k_pack_w<<<dim3(32), dim3(256), 0, stream>>>(w_mix, w_gates, wt_mg);
  k_transpose_bf<<<dim3(NQKV / 32, DIMM / 32), dim3(256), 0, stream>>>(w_qkv, wqkv_t, NQKV, DIMM);
  k_transpose_bf<<<dim3(DIMM / 32, DIMM / 32), dim3(256), 0, stream>>>(w_out, wout_t, DIMM, DIMM);
  k_rmsnorm<<<dim3(MROWS), dim3(256), 0, stream>>>(x, gamma, xn_bf);
  k_mixgates_mfma<<<dim3(MROWS / 32), dim3(64), 0, stream>>>(xn_bf, wt_mg, b_mix, b_gates, mg);
  k_gemm_bf<NQKV, 0><<<dim3(NQKV / 128, MROWS / 128), dim3(256), 0, stream>>>(
      xn_bf, wqkv_t, q_bf, k_bf, v_bf, orig_v, vr, mg, nullptr);
  k_attn<<<dim3(SEQ / 128, NB * HEADS), dim3(256), 0, stream>>>(q_bf, k_bf, v_bf, mg, attn_bf);
  k_gemm_bf<DIMM, 1><<<dim3(DIMM / 128, MROWS / 128), dim3(256), 0, stream>>>(
      attn_bf, wout_t, nullptr, nullptr, nullptr, nullptr, nullptr, nullptr, out);
}